// Round 4
// baseline (340.084 us; speedup 1.0000x reference)
//
#include <hip/hip_runtime.h>
#include <stdint.h>

#define T_DIM 2048
#define B_DIM 16
#define H_DIM 1024
#define M_DIM (T_DIM * B_DIM)   // 32768 rows
#define BK 64
#define TCHUNK 16
#define CONV_BLOCKS 4096
#define CONV_PER_THREAD 4

typedef __attribute__((ext_vector_type(8))) short bf16x8;
typedef __attribute__((ext_vector_type(4))) float floatx4;

__device__ inline unsigned short f2bf(float f) {
  union { float f; unsigned int u; } c; c.f = f;
  unsigned int u = c.u;
  return (unsigned short)((u + 0x7FFFu + ((u >> 16) & 1u)) >> 16);  // RNE
}

__device__ inline float bf2f(unsigned int u16) {
  union { float f; unsigned int u; } c; c.u = u16 << 16;
  return c.f;
}

__device__ inline float fast_tanh(float x) {
  float e = __expf(2.0f * x);
  return 1.0f - 2.0f / (e + 1.0f);
}

__device__ inline void unpack8(uint4 u, float* a) {
  a[0] = bf2f(u.x & 0xffffu); a[1] = bf2f(u.x >> 16);
  a[2] = bf2f(u.y & 0xffffu); a[3] = bf2f(u.y >> 16);
  a[4] = bf2f(u.z & 0xffffu); a[5] = bf2f(u.z >> 16);
  a[6] = bf2f(u.w & 0xffffu); a[7] = bf2f(u.w >> 16);
}

// ---------------- X fp32 -> bf16 (16B stores) + W transpose, one kernel -----
__global__ void prep_kernel(const float* __restrict__ x,
                            uint4* __restrict__ xb16,
                            const float* __restrict__ w,
                            unsigned short* __restrict__ wt) {
  __shared__ float tile[32][33];
  const int bid = blockIdx.x;
  const int tid = threadIdx.x;
  if (bid < CONV_BLOCKS) {
    const float4* x4 = (const float4*)x;
    const size_t stride = (size_t)CONV_BLOCKS * 256;
    size_t t0 = (size_t)bid * 256 + tid;
    #pragma unroll
    for (int it = 0; it < CONV_PER_THREAD; ++it) {
      size_t o = t0 + (size_t)it * stride;      // uint4 (8-elem) index
      float4 lo = x4[o * 2];
      float4 hi = x4[o * 2 + 1];
      uint4 u;
      u.x = ((unsigned)f2bf(lo.y) << 16) | f2bf(lo.x);
      u.y = ((unsigned)f2bf(lo.w) << 16) | f2bf(lo.z);
      u.z = ((unsigned)f2bf(hi.y) << 16) | f2bf(hi.x);
      u.w = ((unsigned)f2bf(hi.w) << 16) | f2bf(hi.z);
      xb16[o] = u;
    }
  } else {
    const int tb = bid - CONV_BLOCKS;           // 0..1023
    const int tx = tid & 31, ty = tid >> 5;     // 32 x 8
    const int n0 = (tb & 31) * 32, k0 = (tb >> 5) * 32;
    for (int i = ty; i < 32; i += 8)
      tile[i][tx] = w[(size_t)(k0 + i) * H_DIM + n0 + tx];
    __syncthreads();
    for (int i = ty; i < 32; i += 8)
      wt[(size_t)(n0 + i) * H_DIM + k0 + tx] = f2bf(tile[tx][i]);
  }
}

// ---------------- scores = tanh(X@W)@proj ----------------
// XCD swizzle: 4 N-splits of one 128-row A-slab land on the same XCD.
// Epilogue writes 8 partial buffers scoresP[(split*2+wx)*M + row] with plain
// stores -> no memset, no atomics. out_kernel sums the 8.
__global__ __launch_bounds__(256, 4)
void score_gemm_kernel(const unsigned short* __restrict__ Xb,
                       const unsigned short* __restrict__ Wt,
                       const float* __restrict__ proj,
                       float* __restrict__ scoresP) {
  __shared__ __align__(16) unsigned short ldsA[128 * BK];
  __shared__ __align__(16) unsigned short ldsB[128 * BK];

  const int tid  = threadIdx.x;
  const int lane = tid & 63;
  const int wave = tid >> 6;
  const int wy = wave >> 1, wx = wave & 1;
  const int quad = lane >> 4, l16 = lane & 15;

  const int idx   = blockIdx.x;
  const int x7    = idx & 7;
  const int split = (idx >> 3) & 3;
  const int g     = idx >> 5;
  const int bm    = g * 8 + x7;        // 0..255
  const int m0    = bm * 128;
  const int nbase = split * 256;

  int ldsOff[4];
  int rowOff[4];
  #pragma unroll
  for (int i = 0; i < 4; ++i) {
    int cb = (i * 4 + wave) * 64;
    int s = cb + lane;
    int row = s >> 3, cs = s & 7;
    int cg = cs ^ (row & 7);
    ldsOff[i] = cb;
    rowOff[i] = row * H_DIM + cg * 8;
  }

  float sc[4][4];
  #pragma unroll
  for (int a = 0; a < 4; ++a)
    #pragma unroll
    for (int b = 0; b < 4; ++b) sc[a][b] = 0.0f;

  for (int n0 = nbase; n0 < nbase + 256; n0 += 128) {
    floatx4 acc[4][4];
    #pragma unroll
    for (int a = 0; a < 4; ++a)
      #pragma unroll
      for (int b = 0; b < 4; ++b) acc[a][b] = (floatx4){0.f, 0.f, 0.f, 0.f};

    for (int k0 = 0; k0 < H_DIM; k0 += BK) {
      #pragma unroll
      for (int i = 0; i < 4; ++i) {
        const unsigned short* ga = Xb + (size_t)m0 * H_DIM + rowOff[i] + k0;
        __builtin_amdgcn_global_load_lds(
            (const __attribute__((address_space(1))) void*)ga,
            (__attribute__((address_space(3))) void*)(&ldsA[ldsOff[i] * 8]),
            16, 0, 0);
        const unsigned short* gb = Wt + (size_t)n0 * H_DIM + rowOff[i] + k0;
        __builtin_amdgcn_global_load_lds(
            (const __attribute__((address_space(1))) void*)gb,
            (__attribute__((address_space(3))) void*)(&ldsB[ldsOff[i] * 8]),
            16, 0, 0);
      }
      __syncthreads();

      #pragma unroll
      for (int kk = 0; kk < BK; kk += 32) {
        const int c = (kk >> 3) + quad;
        bf16x8 af[4], bfr[4];
        #pragma unroll
        for (int rs = 0; rs < 4; ++rs) {
          int r = wy * 64 + rs * 16 + l16;
          af[rs] = *(const bf16x8*)&ldsA[(r * 8 + (c ^ (r & 7))) * 8];
        }
        #pragma unroll
        for (int ns = 0; ns < 4; ++ns) {
          int n = wx * 64 + ns * 16 + l16;
          bfr[ns] = *(const bf16x8*)&ldsB[(n * 8 + (c ^ (n & 7))) * 8];
        }
        #pragma unroll
        for (int rs = 0; rs < 4; ++rs)
          #pragma unroll
          for (int ns = 0; ns < 4; ++ns)
            acc[rs][ns] = __builtin_amdgcn_mfma_f32_16x16x32_bf16(
                af[rs], bfr[ns], acc[rs][ns], 0, 0, 0);
      }
      __syncthreads();
    }

    #pragma unroll
    for (int ns = 0; ns < 4; ++ns) {
      int n = n0 + wx * 64 + ns * 16 + l16;
      float p = proj[n];
      #pragma unroll
      for (int rs = 0; rs < 4; ++rs)
        #pragma unroll
        for (int gg = 0; gg < 4; ++gg)
          sc[rs][gg] += fast_tanh(acc[rs][ns][gg]) * p;
    }
  }

  #pragma unroll
  for (int rs = 0; rs < 4; ++rs)
    #pragma unroll
    for (int gg = 0; gg < 4; ++gg) {
      float v = sc[rs][gg];
      v += __shfl_xor(v, 1);
      v += __shfl_xor(v, 2);
      v += __shfl_xor(v, 4);
      v += __shfl_xor(v, 8);
      if (l16 == 0) {
        int row = m0 + wy * 64 + rs * 16 + quad * 4 + gg;
        scoresP[(size_t)(split * 2 + wx) * M_DIM + row] = v;
      }
    }
}

// ---------------- windowed softmax + weighted sum (bf16 16B taps) -----------
// 128 threads per (t-chunk, b): uint4 tap loads (16 B = 8 bf16). LDS pre-pass
// sums the 8 score partials per t once per block.
__global__ void out_kernel_bf16(const float* __restrict__ x,
                                const uint4* __restrict__ xb16,
                                const float* __restrict__ scoresP,
                                const int* __restrict__ wp,
                                float* __restrict__ out) {
  __shared__ float lds_s[2][TCHUNK + 3];
  int w = *wp;
  const int t0 = blockIdx.x * TCHUNK;
  const int half = threadIdx.x >> 7;          // 0/1
  const int h8 = threadIdx.x & 127;           // 8-elem group index
  const int b = blockIdx.y * 2 + half;
  const float4* x4 = (const float4*)x;
  float4* o4 = (float4*)out;

  // score pre-pass: 70 sums (2 b's x (TCHUNK+3) t's)
  {
    int nsum = 2 * (TCHUNK + 3);
    for (int q = threadIdx.x; q < nsum; q += 256) {
      int bs = q / (TCHUNK + 3);
      int ti = q - bs * (TCHUNK + 3);
      int tm = t0 - 3 + ti;
      float s = 0.f;
      if (tm >= 0) {
        int bb = blockIdx.y * 2 + bs;
        #pragma unroll
        for (int p = 0; p < 8; ++p)
          s += scoresP[(size_t)p * M_DIM + tm * B_DIM + bb];
      }
      lds_s[bs][ti] = s;
    }
    __syncthreads();
  }

  if (w == 3) {
    float a[3][8];
    float s[3];
    #pragma unroll
    for (int j = 0; j < 3; ++j) {
      int tm = t0 - 3 + j;
      s[j] = lds_s[half][j];
      #pragma unroll
      for (int e = 0; e < 8; ++e) a[j][e] = 0.f;
      if (tm >= 0) {
        uint4 u = xb16[((size_t)tm * B_DIM + b) * 128 + h8];
        unpack8(u, a[j]);
      }
    }
    #pragma unroll
    for (int i = 0; i < TCHUNK; ++i) {
      const int t = t0 + i;
      const size_t rowbase = (size_t)t * B_DIM + b;
      uint4 u = xb16[rowbase * 128 + h8];
      float v[8];
      unpack8(u, v);
      float sv = lds_s[half][i + 3];
      const int c0 = i % 3, c1 = (i + 1) % 3, c2 = (i + 2) % 3;
      const size_t rb = rowbase * 256 + h8 * 2;
      if (t < 3) {
        o4[rb] = x4[rb];
        o4[rb + 1] = x4[rb + 1];
      } else {
        float s0 = s[c0], s1 = s[c1], s2 = s[c2];
        float m = fmaxf(fmaxf(s0, s1), s2);
        float e0 = __expf(s0 - m), e1 = __expf(s1 - m), e2 = __expf(s2 - m);
        float inv = 1.0f / (e0 + e1 + e2);
        e0 *= inv; e1 *= inv; e2 *= inv;
        float4 oA, oB;
        oA.x = e0 * a[c0][0] + e1 * a[c1][0] + e2 * a[c2][0];
        oA.y = e0 * a[c0][1] + e1 * a[c1][1] + e2 * a[c2][1];
        oA.z = e0 * a[c0][2] + e1 * a[c1][2] + e2 * a[c2][2];
        oA.w = e0 * a[c0][3] + e1 * a[c1][3] + e2 * a[c2][3];
        oB.x = e0 * a[c0][4] + e1 * a[c1][4] + e2 * a[c2][4];
        oB.y = e0 * a[c0][5] + e1 * a[c1][5] + e2 * a[c2][5];
        oB.z = e0 * a[c0][6] + e1 * a[c1][6] + e2 * a[c2][6];
        oB.w = e0 * a[c0][7] + e1 * a[c1][7] + e2 * a[c2][7];
        o4[rb] = oA;
        o4[rb + 1] = oB;
      }
      #pragma unroll
      for (int e = 0; e < 8; ++e) a[c0][e] = v[e];
      s[c0] = sv;
    }
  } else {
    if (w > 8) w = 8;
    for (int i = 0; i < TCHUNK; ++i) {
      int t = t0 + i;
      size_t rb = ((size_t)t * B_DIM + b) * 256 + h8 * 2;
      if (t < w) { o4[rb] = x4[rb]; o4[rb + 1] = x4[rb + 1]; continue; }
      float sw[8];
      float mx = -1e30f;
      for (int j = 0; j < w; ++j) {
        float s = 0.f;
        #pragma unroll
        for (int p = 0; p < 8; ++p)
          s += scoresP[(size_t)p * M_DIM + (t - w + j) * B_DIM + b];
        sw[j] = s;
        mx = fmaxf(mx, s);
      }
      float sum = 0.f;
      for (int j = 0; j < w; ++j) { sw[j] = __expf(sw[j] - mx); sum += sw[j]; }
      float inv = 1.0f / sum;
      float4 oA = {0.f, 0.f, 0.f, 0.f}, oB = {0.f, 0.f, 0.f, 0.f};
      for (int j = 0; j < w; ++j) {
        float aw = sw[j] * inv;
        size_t tb = ((size_t)(t - w + j) * B_DIM + b) * 256 + h8 * 2;
        float4 vA = x4[tb], vB = x4[tb + 1];
        oA.x += aw * vA.x; oA.y += aw * vA.y; oA.z += aw * vA.z; oA.w += aw * vA.w;
        oB.x += aw * vB.x; oB.y += aw * vB.y; oB.z += aw * vB.z; oB.w += aw * vB.w;
      }
      o4[rb] = oA;
      o4[rb + 1] = oB;
    }
  }
}

// ---------------- fp32-tap fallback (Xb aliases d_out) ----------------------
__global__ void out_kernel_f32(const float* __restrict__ x,
                               const float* __restrict__ scoresP,
                               const int* __restrict__ wp,
                               float* __restrict__ out) {
  int w = *wp;
  int t0 = blockIdx.x * TCHUNK;
  int b  = blockIdx.y;
  int h  = threadIdx.x;
  const float4* x4 = (const float4*)x;
  float4* o4 = (float4*)out;

  if (w > 8) w = 8;
  for (int i = 0; i < TCHUNK; ++i) {
    int t = t0 + i;
    size_t rbase = ((size_t)t * B_DIM + b) * 256 + h;
    if (t < w) { o4[rbase] = x4[rbase]; continue; }
    float s[8];
    float mx = -1e30f;
    for (int j = 0; j < w; ++j) {
      float sv = 0.f;
      #pragma unroll
      for (int p = 0; p < 8; ++p)
        sv += scoresP[(size_t)p * M_DIM + (t - w + j) * B_DIM + b];
      s[j] = sv;
      mx = fmaxf(mx, sv);
    }
    float sum = 0.f;
    for (int j = 0; j < w; ++j) { s[j] = __expf(s[j] - mx); sum += s[j]; }
    float inv = 1.0f / sum;
    float4 o = {0.f, 0.f, 0.f, 0.f};
    for (int j = 0; j < w; ++j) {
      float a = s[j] * inv;
      float4 v = x4[((size_t)(t - w + j) * B_DIM + b) * 256 + h];
      o.x += a * v.x; o.y += a * v.y; o.z += a * v.z; o.w += a * v.w;
    }
    o4[rbase] = o;
  }
}

extern "C" void kernel_launch(void* const* d_in, const int* in_sizes, int n_in,
                              void* d_out, int out_size, void* d_ws, size_t ws_size,
                              hipStream_t stream) {
  const float* x    = (const float*)d_in[0];
  const float* w    = (const float*)d_in[1];
  const float* proj = (const float*)d_in[2];
  const int*   wp   = (const int*)d_in[3];
  float* out = (float*)d_out;

  const size_t XB_BYTES = (size_t)64 * 1024 * 1024;
  const size_t WT_BYTES = (size_t)2 * 1024 * 1024;
  const size_t SP_BYTES = (size_t)8 * M_DIM * sizeof(float);   // 1 MiB
  const size_t need = XB_BYTES + WT_BYTES + SP_BYTES;
  const bool use_ws = ws_size >= need;

  unsigned short* Xb;
  unsigned short* Wt;
  float* scoresP;
  if (use_ws) {
    Xb = (unsigned short*)d_ws;
    Wt = (unsigned short*)((char*)d_ws + XB_BYTES);
    scoresP = (float*)((char*)d_ws + XB_BYTES + WT_BYTES);
  } else {
    Xb = (unsigned short*)d_out;
    Wt = (unsigned short*)((char*)d_out + XB_BYTES);
    scoresP = (float*)d_ws;
  }

  prep_kernel<<<CONV_BLOCKS + 1024, 256, 0, stream>>>(x, (uint4*)Xb, w, Wt);
  score_gemm_kernel<<<1024, 256, 0, stream>>>(Xb, Wt, proj, scoresP);
  if (use_ws)
    out_kernel_bf16<<<dim3(T_DIM / TCHUNK, B_DIM / 2), 256, 0, stream>>>(
        x, (const uint4*)Xb, scoresP, wp, out);
  else
    out_kernel_f32<<<dim3(T_DIM / TCHUNK, B_DIM), 256, 0, stream>>>(
        x, scoresP, wp, out);
}